// Round 6
// baseline (12904.897 us; speedup 1.0000x reference)
//
#include <hip/hip_runtime.h>
#include <cstdint>

// Problem constants: D=512, H=2048, T=2048, O=512, 4H=8192.
#define H_DIM 2048
#define H4_DIM 8192
#define T_LEN 2048
#define NREP 8           // slot replicas (per-XCD contention spreading)

typedef unsigned long long u64;
typedef __attribute__((ext_vector_type(2))) float v2f;

__device__ __forceinline__ float sigmoid_f(float x) {
  return 1.0f / (1.0f + __expf(-x));
}
__device__ __forceinline__ float tanh_f(float x) {
  float ax = fabsf(x);
  float e = __expf(-2.0f * ax);
  float r = (1.0f - e) / (1.0f + e);
  return copysignf(r, x);
}

// ---- persistent LSTM recurrence, weights register-resident, NO barrier ----
// Cross-step exchange: slot[rep][parity][j] = (tag<<32)|bits(h_j), relaxed
// agent 64-bit atomics. Slots replicated 8x (producers: lanes 0..7 store to
// all replicas; consumers poll replica blockIdx&7 -> fan-in 32).
// Parity double-buffer + all-to-all dependence forbids overwrite-before-read;
// 0xAAAAAAAA poison never matches tags 1..2048 -> no init needed.
//
// r6: (a) software-pipelined poll -- two batches in flight, vote waits only
// on the older batch (vmcnt(4)), cadence ~100cy instead of full RTT;
// (b) xp prefetched one step ahead AFTER poll-exit, so FIFO vmcnt waits in
// the poll loop never drain an in-flight xp miss.
__global__ __launch_bounds__(512, 2) void lstm_rec(
    const float* __restrict__ Whh,   // (8192, 2048)
    const float* __restrict__ xp,    // (T, 8192) x-projection + biases
    u64* __restrict__ slots,         // NREP * 2 * 2048 tagged h slots
    float* __restrict__ ys,          // (T, 2048) or nullptr
    int T)
{
  __shared__ float hl[H_DIM];
  const int g = blockIdx.x;
  const int tid = threadIdx.x;
  const int w = tid >> 6;
  const int l = tid & 63;
  const int j = g * 8 + w;
  const int rep = g & (NREP - 1);

  // one-time weight load (each element read exactly once grid-wide),
  // packed as float2 for v_pk_fma_f32
  v2f wreg[64];
  #pragma unroll
  for (int q = 0; q < 4; ++q) {
    const float* wr = Whh + (size_t)(j + q * H_DIM) * H_DIM + l * 4;
    #pragma unroll
    for (int k = 0; k < 8; ++k) {
      float4 v = *(const float4*)(wr + 256 * k);
      v2f lo; lo.x = v.x; lo.y = v.y;
      v2f hi; hi.x = v.z; hi.y = v.w;
      wreg[q * 16 + k * 2 + 0] = lo;
      wreg[q * 16 + k * 2 + 1] = hi;
    }
  }

  float c = 0.0f;

  // xq for step 0, loaded pre-loop (lanes 0..7; broadcast lines)
  float xq0 = 0.f, xq1 = 0.f, xq2 = 0.f, xq3 = 0.f;
  if (l < NREP) {
    xq0 = xp[j];
    xq1 = xp[j + H_DIM];
    xq2 = xp[j + 2 * H_DIM];
    xq3 = xp[j + 3 * H_DIM];
  }

  for (int t = 0; t < T; ++t) {
    if (t == 0) {
      ((float4*)hl)[tid] = make_float4(0.f, 0.f, 0.f, 0.f);  // h_0 = 0
    } else {
      // consume h_t from my replica: software-pipelined poll (2 batches in
      // flight; the vote's vmcnt wait drains only the older batch)
      const u64* S = slots + ((size_t)(rep * 2 + (t & 1))) * H_DIM + tid;
      u64 v0 = __hip_atomic_load(S, __ATOMIC_RELAXED, __HIP_MEMORY_SCOPE_AGENT);
      u64 v1 = __hip_atomic_load(S + 512, __ATOMIC_RELAXED, __HIP_MEMORY_SCOPE_AGENT);
      u64 v2 = __hip_atomic_load(S + 1024, __ATOMIC_RELAXED, __HIP_MEMORY_SCOPE_AGENT);
      u64 v3 = __hip_atomic_load(S + 1536, __ATOMIC_RELAXED, __HIP_MEMORY_SCOPE_AGENT);
      for (;;) {
        u64 n0 = __hip_atomic_load(S, __ATOMIC_RELAXED, __HIP_MEMORY_SCOPE_AGENT);
        u64 n1 = __hip_atomic_load(S + 512, __ATOMIC_RELAXED, __HIP_MEMORY_SCOPE_AGENT);
        u64 n2 = __hip_atomic_load(S + 1024, __ATOMIC_RELAXED, __HIP_MEMORY_SCOPE_AGENT);
        u64 n3 = __hip_atomic_load(S + 1536, __ATOMIC_RELAXED, __HIP_MEMORY_SCOPE_AGENT);
        bool ok = ((unsigned)(v0 >> 32) == (unsigned)t) &
                  ((unsigned)(v1 >> 32) == (unsigned)t) &
                  ((unsigned)(v2 >> 32) == (unsigned)t) &
                  ((unsigned)(v3 >> 32) == (unsigned)t);
        if (__all(ok)) break;
        v0 = n0; v1 = n1; v2 = n2; v3 = n3;
      }
      hl[tid]        = __uint_as_float((unsigned)v0);
      hl[tid + 512]  = __uint_as_float((unsigned)v1);
      hl[tid + 1024] = __uint_as_float((unsigned)v2);
      hl[tid + 1536] = __uint_as_float((unsigned)v3);
    }

    // prefetch NEXT step's xq now (issued after poll-exit: this step's poll
    // never drains it; completes well before step t+1's first poll wait)
    float nxq0 = 0.f, nxq1 = 0.f, nxq2 = 0.f, nxq3 = 0.f;
    if (l < NREP && t + 1 < T) {
      const float* xrow = xp + (size_t)(t + 1) * H4_DIM + j;
      nxq0 = xrow[0];
      nxq1 = xrow[H_DIM];
      nxq2 = xrow[2 * H_DIM];
      nxq3 = xrow[3 * H_DIM];
    }
    __syncthreads();

    // packed matvec: 64 v_pk_fma_f32 per thread (4 gates x 16)
    v2f a0 = {0.f, 0.f}, a1 = {0.f, 0.f}, a2 = {0.f, 0.f}, a3 = {0.f, 0.f};
    #pragma unroll
    for (int k = 0; k < 8; ++k) {
      float4 h4 = ((const float4*)hl)[l + 64 * k];
      v2f hlo; hlo.x = h4.x; hlo.y = h4.y;
      v2f hhi; hhi.x = h4.z; hhi.y = h4.w;
      a0 = __builtin_elementwise_fma(wreg[0 + k * 2], hlo, a0);
      a0 = __builtin_elementwise_fma(wreg[1 + k * 2], hhi, a0);
      a1 = __builtin_elementwise_fma(wreg[16 + k * 2], hlo, a1);
      a1 = __builtin_elementwise_fma(wreg[17 + k * 2], hhi, a1);
      a2 = __builtin_elementwise_fma(wreg[32 + k * 2], hlo, a2);
      a2 = __builtin_elementwise_fma(wreg[33 + k * 2], hhi, a2);
      a3 = __builtin_elementwise_fma(wreg[48 + k * 2], hlo, a3);
      a3 = __builtin_elementwise_fma(wreg[49 + k * 2], hhi, a3);
    }
    float acc0 = a0.x + a0.y;
    float acc1 = a1.x + a1.y;
    float acc2 = a2.x + a2.y;
    float acc3 = a3.x + a3.y;

    // 64-lane butterfly ALLreduce (every lane ends with the full 4 dots)
    #pragma unroll
    for (int off = 32; off; off >>= 1) {
      acc0 += __shfl_xor(acc0, off);
      acc1 += __shfl_xor(acc1, off);
      acc2 += __shfl_xor(acc2, off);
      acc3 += __shfl_xor(acc3, off);
    }

    // gates on all lanes (replicated; bit-identical on lanes 0..7 which hold
    // real xq); lane k<8 publishes to replica k; lane 0 writes ys
    float i_ = sigmoid_f(acc0 + xq0);
    float f_ = sigmoid_f(acc1 + xq1);
    float g_ = tanh_f(acc2 + xq2);
    float o_ = sigmoid_f(acc3 + xq3);
    c = f_ * c + i_ * g_;
    float h_ = o_ * tanh_f(c);

    if (l < NREP) {
      union { float f; unsigned u; } cv;
      cv.f = h_;
      u64 pv = ((u64)(unsigned)(t + 1) << 32) | (u64)cv.u;
      __hip_atomic_store(
          slots + ((size_t)(l * 2 + ((t + 1) & 1))) * H_DIM + j, pv,
          __ATOMIC_RELAXED, __HIP_MEMORY_SCOPE_AGENT);
      if (l == 0 && ys) ys[(size_t)t * H_DIM + j] = h_;
    }
    xq0 = nxq0; xq1 = nxq1; xq2 = nxq2; xq3 = nxq3;
    // all waves must finish reading hl before next step's poll overwrites it
    __syncthreads();
  }
}

// ---- fp32 GEMM: C[M][N] = A[M][K] @ W[N][K]^T + b0[n] + b1[n] ----
// 128x128 tile, 256 threads, 8x8 microtile, BK=8.
__global__ __launch_bounds__(256) void gemm_bt_bias(
    const float* __restrict__ A, const float* __restrict__ W,
    const float* __restrict__ b0, const float* __restrict__ b1,
    float* __restrict__ C, int M, int N, int K)
{
  __shared__ float As[8][128];
  __shared__ float Bs[8][128];
  const int tid = threadIdx.x;
  const int n0 = blockIdx.x * 128;
  const int m0 = blockIdx.y * 128;
  const int tx = tid & 15;   // n direction
  const int ty = tid >> 4;   // m direction
  const int lr = tid >> 1;   // loader row 0..127
  const int lk = (tid & 1) * 4;
  const float* Ap = A + (size_t)(m0 + lr) * K + lk;
  const float* Wp = W + (size_t)(n0 + lr) * K + lk;

  float acc[8][8];
  #pragma unroll
  for (int i = 0; i < 8; ++i)
    #pragma unroll
    for (int jj = 0; jj < 8; ++jj) acc[i][jj] = 0.f;

  for (int kt = 0; kt < K; kt += 8) {
    float4 av = *(const float4*)(Ap + kt);
    float4 wv = *(const float4*)(Wp + kt);
    __syncthreads();
    As[lk + 0][lr] = av.x; As[lk + 1][lr] = av.y;
    As[lk + 2][lr] = av.z; As[lk + 3][lr] = av.w;
    Bs[lk + 0][lr] = wv.x; Bs[lk + 1][lr] = wv.y;
    Bs[lk + 2][lr] = wv.z; Bs[lk + 3][lr] = wv.w;
    __syncthreads();
    #pragma unroll
    for (int k = 0; k < 8; ++k) {
      float a[8], b[8];
      *(float4*)&a[0] = *(const float4*)&As[k][ty * 8];
      *(float4*)&a[4] = *(const float4*)&As[k][ty * 8 + 4];
      *(float4*)&b[0] = *(const float4*)&Bs[k][tx * 8];
      *(float4*)&b[4] = *(const float4*)&Bs[k][tx * 8 + 4];
      #pragma unroll
      for (int i = 0; i < 8; ++i)
        #pragma unroll
        for (int jj = 0; jj < 8; ++jj)
          acc[i][jj] = fmaf(a[i], b[jj], acc[i][jj]);
    }
  }

  const int n = n0 + tx * 8;
  float bias[8];
  #pragma unroll
  for (int jj = 0; jj < 8; ++jj)
    bias[jj] = b0[n + jj] + (b1 ? b1[n + jj] : 0.f);
  #pragma unroll
  for (int i = 0; i < 8; ++i) {
    float* crow = C + (size_t)(m0 + ty * 8 + i) * N + n;
    float4 v0 = make_float4(acc[i][0] + bias[0], acc[i][1] + bias[1],
                            acc[i][2] + bias[2], acc[i][3] + bias[3]);
    float4 v1 = make_float4(acc[i][4] + bias[4], acc[i][5] + bias[5],
                            acc[i][6] + bias[6], acc[i][7] + bias[7]);
    *(float4*)crow = v0;
    *(float4*)(crow + 4) = v1;
  }
}

// ---- final FC: out[o] = dot(h_last, fc_w[o]) + fc_b[o], one wave/output ----
// h_last read from layer-1 tagged slots, replica 0, parity 0 (tag T).
__global__ void fc_kernel(const u64* __restrict__ hslots,
                          const float* __restrict__ Wf,
                          const float* __restrict__ bf,
                          float* __restrict__ out)
{
  const int o = blockIdx.x;
  const int l = threadIdx.x;
  const float* wr = Wf + (size_t)o * H_DIM;
  float s = 0.f;
  #pragma unroll
  for (int k = 0; k < 32; ++k) {
    union { unsigned u; float f; } cv;
    cv.u = (unsigned)hslots[l + 64 * k];
    s = fmaf(wr[l + 64 * k], cv.f, s);
  }
  #pragma unroll
  for (int off = 32; off; off >>= 1) s += __shfl_xor(s, off);
  if (l == 0) out[o] = s + bf[o];
}

extern "C" void kernel_launch(void* const* d_in, const int* in_sizes, int n_in,
                              void* d_out, int out_size, void* d_ws, size_t ws_size,
                              hipStream_t stream) {
  const float* x    = (const float*)d_in[0];
  const float* Wih0 = (const float*)d_in[1];
  const float* Whh0 = (const float*)d_in[2];
  const float* bih0 = (const float*)d_in[3];
  const float* bhh0 = (const float*)d_in[4];
  const float* Wih1 = (const float*)d_in[5];
  const float* Whh1 = (const float*)d_in[6];
  const float* bih1 = (const float*)d_in[7];
  const float* bhh1 = (const float*)d_in[8];
  const float* fcw  = (const float*)d_in[9];
  const float* fcb  = (const float*)d_in[10];
  float* out = (float*)d_out;

  // workspace layout (floats): ~85 MB
  float* ws   = (float*)d_ws;
  float* xp   = ws;                      // (2048, 8192) = 16777216
  float* ys   = ws + 16777216;           // (2048, 2048) =  4194304
  u64* slots0 = (u64*)(ws + 20971520);   // NREP x 2 x 2048 tagged h (256 KB)
  u64* slots1 = slots0 + NREP * 2 * H_DIM;  // layer 1 (fresh poison)

  dim3 gblk(256);
  dim3 ggrid(H4_DIM / 128, T_LEN / 128);  // (64, 16)

  // layer 0: xp = x @ Wih0^T + (bih0+bhh0); recurrence -> ys
  gemm_bt_bias<<<ggrid, gblk, 0, stream>>>(x, Wih0, bih0, bhh0, xp,
                                           T_LEN, H4_DIM, 512);
  lstm_rec<<<256, 512, 0, stream>>>(Whh0, xp, slots0, ys, T_LEN);

  // layer 1: xp = ys @ Wih1^T + (bih1+bhh1); recurrence, keep only h_last
  gemm_bt_bias<<<ggrid, gblk, 0, stream>>>(ys, Wih1, bih1, bhh1, xp,
                                           T_LEN, H4_DIM, H_DIM);
  lstm_rec<<<256, 512, 0, stream>>>(Whh1, xp, slots1, nullptr, T_LEN);

  // h_last of layer 1: slots1 replica 0, parity (T&1)=0, tag T
  fc_kernel<<<512, 64, 0, stream>>>(slots1, fcw, fcb, out);
}

// Round 7
// 12588.558 us; speedup vs baseline: 1.0251x; 1.0251x over previous
//
#include <hip/hip_runtime.h>
#include <cstdint>

// Problem constants: D=512, H=2048, T=2048, O=512, 4H=8192.
#define H_DIM 2048
#define H4_DIM 8192
#define T_LEN 2048
#define NREP 8           // slot replicas (per-XCD contention spreading)

typedef unsigned long long u64;
typedef __attribute__((ext_vector_type(2))) float v2f;

__device__ __forceinline__ float sigmoid_f(float x) {
  return 1.0f / (1.0f + __expf(-x));
}
__device__ __forceinline__ float tanh_f(float x) {
  float ax = fabsf(x);
  float e = __expf(-2.0f * ax);
  float r = (1.0f - e) / (1.0f + e);
  return copysignf(r, x);
}

// ---- persistent LSTM recurrence, weights register-resident, NO barrier ----
// Cross-step exchange (r7 = r5 + seq digest):
//  * tagged h slots: slot[rep][parity][j] = (tag<<32)|bits(h_j), relaxed
//    agent 64-bit atomics, 8x replicated (consumers use replica g&7).
//    Parity double-buffer + all-to-all dependence forbids
//    overwrite-before-read; 0xAAAAAAAA poison never matches tags 1..2048.
//  * NEW: per-block seq digest seq[rep][g] (packed u32, 8x replicated),
//    published by wave 0 AFTER the tail __syncthreads (whose compiler-
//    emitted vmcnt(0) drain guarantees all 8 waves' h stores are acked).
//    Consumers poll ONLY the 1KB digest (1 word/thread, coalesced ->
//    16 fabric transactions per block-round, 8x less than polling the
//    16KB slot array), then do a single-shot tagged bulk read of h.
//    The tag-verify fallback keeps correctness independent of any
//    digest/h store-visibility reordering.
__global__ __launch_bounds__(512, 2) void lstm_rec(
    const float* __restrict__ Whh,   // (8192, 2048)
    const float* __restrict__ xp,    // (T, 8192) x-projection + biases
    u64* __restrict__ slots,         // NREP * 2 * 2048 tagged h slots
    unsigned* __restrict__ seq,      // NREP * 256 per-block step digest
    float* __restrict__ ys,          // (T, 2048) or nullptr
    int T)
{
  __shared__ float hl[H_DIM];
  const int g = blockIdx.x;
  const int tid = threadIdx.x;
  const int w = tid >> 6;
  const int l = tid & 63;
  const int j = g * 8 + w;
  const int rep = g & (NREP - 1);

  // one-time weight load (each element read exactly once grid-wide),
  // packed as float2 for v_pk_fma_f32
  v2f wreg[64];
  #pragma unroll
  for (int q = 0; q < 4; ++q) {
    const float* wr = Whh + (size_t)(j + q * H_DIM) * H_DIM + l * 4;
    #pragma unroll
    for (int k = 0; k < 8; ++k) {
      float4 v = *(const float4*)(wr + 256 * k);
      v2f lo; lo.x = v.x; lo.y = v.y;
      v2f hi; hi.x = v.z; hi.y = v.w;
      wreg[q * 16 + k * 2 + 0] = lo;
      wreg[q * 16 + k * 2 + 1] = hi;
    }
  }

  float c = 0.0f;

  for (int t = 0; t < T; ++t) {
    // prefetch this step's x-projection early (lanes 0..7; broadcast lines;
    // the poll loop's waits cover the HBM latency)
    float xq0 = 0.f, xq1 = 0.f, xq2 = 0.f, xq3 = 0.f;
    if (l < NREP) {
      const float* xrow = xp + (size_t)t * H4_DIM + j;
      xq0 = xrow[0];
      xq1 = xrow[H_DIM];
      xq2 = xrow[2 * H_DIM];
      xq3 = xrow[3 * H_DIM];
    }

    if (t == 0) {
      ((float4*)hl)[tid] = make_float4(0.f, 0.f, 0.f, 0.f);  // h_0 = 0
      __syncthreads();
    } else {
      // phase 1: poll the compact digest (monotonic >=, poison-safe:
      // (int)(0xAAAAAAAA - t) < 0)
      const unsigned* SQ = seq + rep * 256 + (tid & 255);
      for (;;) {
        unsigned s = __hip_atomic_load(SQ, __ATOMIC_RELAXED,
                                       __HIP_MEMORY_SCOPE_AGENT);
        if (__all((int)(s - (unsigned)t) >= 0)) break;
        __builtin_amdgcn_s_sleep(1);
      }
      __syncthreads();   // all 256 blocks confirmed by some wave

      // phase 2: single-shot tagged bulk read (tag-verify fallback loop;
      // expected to exit in ~1 round)
      const u64* S = slots + ((size_t)(rep * 2 + (t & 1))) * H_DIM + tid;
      u64 v0, v1, v2, v3;
      for (;;) {
        v0 = __hip_atomic_load(S, __ATOMIC_RELAXED, __HIP_MEMORY_SCOPE_AGENT);
        v1 = __hip_atomic_load(S + 512, __ATOMIC_RELAXED, __HIP_MEMORY_SCOPE_AGENT);
        v2 = __hip_atomic_load(S + 1024, __ATOMIC_RELAXED, __HIP_MEMORY_SCOPE_AGENT);
        v3 = __hip_atomic_load(S + 1536, __ATOMIC_RELAXED, __HIP_MEMORY_SCOPE_AGENT);
        bool ok = ((unsigned)(v0 >> 32) == (unsigned)t) &
                  ((unsigned)(v1 >> 32) == (unsigned)t) &
                  ((unsigned)(v2 >> 32) == (unsigned)t) &
                  ((unsigned)(v3 >> 32) == (unsigned)t);
        if (__all(ok)) break;
      }
      hl[tid]        = __uint_as_float((unsigned)v0);
      hl[tid + 512]  = __uint_as_float((unsigned)v1);
      hl[tid + 1024] = __uint_as_float((unsigned)v2);
      hl[tid + 1536] = __uint_as_float((unsigned)v3);
      __syncthreads();
    }

    // packed matvec: 64 v_pk_fma_f32 per thread (4 gates x 16)
    v2f a0 = {0.f, 0.f}, a1 = {0.f, 0.f}, a2 = {0.f, 0.f}, a3 = {0.f, 0.f};
    #pragma unroll
    for (int k = 0; k < 8; ++k) {
      float4 h4 = ((const float4*)hl)[l + 64 * k];
      v2f hlo; hlo.x = h4.x; hlo.y = h4.y;
      v2f hhi; hhi.x = h4.z; hhi.y = h4.w;
      a0 = __builtin_elementwise_fma(wreg[0 + k * 2], hlo, a0);
      a0 = __builtin_elementwise_fma(wreg[1 + k * 2], hhi, a0);
      a1 = __builtin_elementwise_fma(wreg[16 + k * 2], hlo, a1);
      a1 = __builtin_elementwise_fma(wreg[17 + k * 2], hhi, a1);
      a2 = __builtin_elementwise_fma(wreg[32 + k * 2], hlo, a2);
      a2 = __builtin_elementwise_fma(wreg[33 + k * 2], hhi, a2);
      a3 = __builtin_elementwise_fma(wreg[48 + k * 2], hlo, a3);
      a3 = __builtin_elementwise_fma(wreg[49 + k * 2], hhi, a3);
    }
    float acc0 = a0.x + a0.y;
    float acc1 = a1.x + a1.y;
    float acc2 = a2.x + a2.y;
    float acc3 = a3.x + a3.y;

    // 64-lane butterfly ALLreduce (every lane ends with the full 4 dots)
    #pragma unroll
    for (int off = 32; off; off >>= 1) {
      acc0 += __shfl_xor(acc0, off);
      acc1 += __shfl_xor(acc1, off);
      acc2 += __shfl_xor(acc2, off);
      acc3 += __shfl_xor(acc3, off);
    }

    // gates on all lanes (replicated; bit-identical on lanes 0..7 which hold
    // real xq); lane k<8 publishes to replica k; lane 0 writes ys
    float i_ = sigmoid_f(acc0 + xq0);
    float f_ = sigmoid_f(acc1 + xq1);
    float g_ = tanh_f(acc2 + xq2);
    float o_ = sigmoid_f(acc3 + xq3);
    c = f_ * c + i_ * g_;
    float h_ = o_ * tanh_f(c);

    if (l < NREP) {
      union { float f; unsigned u; } cv;
      cv.f = h_;
      u64 pv = ((u64)(unsigned)(t + 1) << 32) | (u64)cv.u;
      __hip_atomic_store(
          slots + ((size_t)(l * 2 + ((t + 1) & 1))) * H_DIM + j, pv,
          __ATOMIC_RELAXED, __HIP_MEMORY_SCOPE_AGENT);
      if (l == 0 && ys) ys[(size_t)t * H_DIM + j] = h_;
    }
    // tail sync: also drains vmcnt -> all 8 waves' h stores are acked
    // before wave 0 publishes the digest below
    __syncthreads();
    if (w == 0 && l < NREP) {
      __hip_atomic_store(seq + l * 256 + g, (unsigned)(t + 1),
                         __ATOMIC_RELAXED, __HIP_MEMORY_SCOPE_AGENT);
    }
  }
}

// ---- fp32 GEMM: C[M][N] = A[M][K] @ W[N][K]^T + b0[n] + b1[n] ----
// 128x128 tile, 256 threads, 8x8 microtile, BK=8.
__global__ __launch_bounds__(256) void gemm_bt_bias(
    const float* __restrict__ A, const float* __restrict__ W,
    const float* __restrict__ b0, const float* __restrict__ b1,
    float* __restrict__ C, int M, int N, int K)
{
  __shared__ float As[8][128];
  __shared__ float Bs[8][128];
  const int tid = threadIdx.x;
  const int n0 = blockIdx.x * 128;
  const int m0 = blockIdx.y * 128;
  const int tx = tid & 15;   // n direction
  const int ty = tid >> 4;   // m direction
  const int lr = tid >> 1;   // loader row 0..127
  const int lk = (tid & 1) * 4;
  const float* Ap = A + (size_t)(m0 + lr) * K + lk;
  const float* Wp = W + (size_t)(n0 + lr) * K + lk;

  float acc[8][8];
  #pragma unroll
  for (int i = 0; i < 8; ++i)
    #pragma unroll
    for (int jj = 0; jj < 8; ++jj) acc[i][jj] = 0.f;

  for (int kt = 0; kt < K; kt += 8) {
    float4 av = *(const float4*)(Ap + kt);
    float4 wv = *(const float4*)(Wp + kt);
    __syncthreads();
    As[lk + 0][lr] = av.x; As[lk + 1][lr] = av.y;
    As[lk + 2][lr] = av.z; As[lk + 3][lr] = av.w;
    Bs[lk + 0][lr] = wv.x; Bs[lk + 1][lr] = wv.y;
    Bs[lk + 2][lr] = wv.z; Bs[lk + 3][lr] = wv.w;
    __syncthreads();
    #pragma unroll
    for (int k = 0; k < 8; ++k) {
      float a[8], b[8];
      *(float4*)&a[0] = *(const float4*)&As[k][ty * 8];
      *(float4*)&a[4] = *(const float4*)&As[k][ty * 8 + 4];
      *(float4*)&b[0] = *(const float4*)&Bs[k][tx * 8];
      *(float4*)&b[4] = *(const float4*)&Bs[k][tx * 8 + 4];
      #pragma unroll
      for (int i = 0; i < 8; ++i)
        #pragma unroll
        for (int jj = 0; jj < 8; ++jj)
          acc[i][jj] = fmaf(a[i], b[jj], acc[i][jj]);
    }
  }

  const int n = n0 + tx * 8;
  float bias[8];
  #pragma unroll
  for (int jj = 0; jj < 8; ++jj)
    bias[jj] = b0[n + jj] + (b1 ? b1[n + jj] : 0.f);
  #pragma unroll
  for (int i = 0; i < 8; ++i) {
    float* crow = C + (size_t)(m0 + ty * 8 + i) * N + n;
    float4 v0 = make_float4(acc[i][0] + bias[0], acc[i][1] + bias[1],
                            acc[i][2] + bias[2], acc[i][3] + bias[3]);
    float4 v1 = make_float4(acc[i][4] + bias[4], acc[i][5] + bias[5],
                            acc[i][6] + bias[6], acc[i][7] + bias[7]);
    *(float4*)crow = v0;
    *(float4*)(crow + 4) = v1;
  }
}

// ---- final FC: out[o] = dot(h_last, fc_w[o]) + fc_b[o], one wave/output ----
// h_last read from layer-1 tagged slots, replica 0, parity 0 (tag T).
__global__ void fc_kernel(const u64* __restrict__ hslots,
                          const float* __restrict__ Wf,
                          const float* __restrict__ bf,
                          float* __restrict__ out)
{
  const int o = blockIdx.x;
  const int l = threadIdx.x;
  const float* wr = Wf + (size_t)o * H_DIM;
  float s = 0.f;
  #pragma unroll
  for (int k = 0; k < 32; ++k) {
    union { unsigned u; float f; } cv;
    cv.u = (unsigned)hslots[l + 64 * k];
    s = fmaf(wr[l + 64 * k], cv.f, s);
  }
  #pragma unroll
  for (int off = 32; off; off >>= 1) s += __shfl_xor(s, off);
  if (l == 0) out[o] = s + bf[o];
}

extern "C" void kernel_launch(void* const* d_in, const int* in_sizes, int n_in,
                              void* d_out, int out_size, void* d_ws, size_t ws_size,
                              hipStream_t stream) {
  const float* x    = (const float*)d_in[0];
  const float* Wih0 = (const float*)d_in[1];
  const float* Whh0 = (const float*)d_in[2];
  const float* bih0 = (const float*)d_in[3];
  const float* bhh0 = (const float*)d_in[4];
  const float* Wih1 = (const float*)d_in[5];
  const float* Whh1 = (const float*)d_in[6];
  const float* bih1 = (const float*)d_in[7];
  const float* bhh1 = (const float*)d_in[8];
  const float* fcw  = (const float*)d_in[9];
  const float* fcb  = (const float*)d_in[10];
  float* out = (float*)d_out;

  // workspace layout (floats): ~85 MB
  float* ws   = (float*)d_ws;
  float* xp   = ws;                      // (2048, 8192) = 16777216
  float* ys   = ws + 16777216;           // (2048, 2048) =  4194304
  u64* slots0 = (u64*)(ws + 20971520);   // NREP x 2 x 2048 tagged h (256 KB)
  u64* slots1 = slots0 + NREP * 2 * H_DIM;
  unsigned* seq0 = (unsigned*)(slots1 + NREP * 2 * H_DIM);  // NREP x 256 u32
  unsigned* seq1 = seq0 + NREP * 256;

  dim3 gblk(256);
  dim3 ggrid(H4_DIM / 128, T_LEN / 128);  // (64, 16)

  // layer 0: xp = x @ Wih0^T + (bih0+bhh0); recurrence -> ys
  gemm_bt_bias<<<ggrid, gblk, 0, stream>>>(x, Wih0, bih0, bhh0, xp,
                                           T_LEN, H4_DIM, 512);
  lstm_rec<<<256, 512, 0, stream>>>(Whh0, xp, slots0, seq0, ys, T_LEN);

  // layer 1: xp = ys @ Wih1^T + (bih1+bhh1); recurrence, keep only h_last
  gemm_bt_bias<<<ggrid, gblk, 0, stream>>>(ys, Wih1, bih1, bhh1, xp,
                                           T_LEN, H4_DIM, H_DIM);
  lstm_rec<<<256, 512, 0, stream>>>(Whh1, xp, slots1, seq1, nullptr, T_LEN);

  // h_last of layer 1: slots1 replica 0, parity (T&1)=0, tag T
  fc_kernel<<<512, 64, 0, stream>>>(slots1, fcw, fcb, out);
}